// Round 5
// baseline (537.534 us; speedup 1.0000x reference)
//
#include <hip/hip_runtime.h>
#include <math.h>

namespace {
constexpr int Bsz = 4;
constexpr int T   = 2048;
constexpr int C   = 1024;
constexpr int H   = 16;
constexpr int HD  = 64;

typedef short bf16x8 __attribute__((ext_vector_type(8)));
typedef float f32x4  __attribute__((ext_vector_type(4)));

#if defined(__has_builtin)
#if __has_builtin(__builtin_amdgcn_global_load_lds)
#define HAVE_GLL 1
typedef __attribute__((address_space(3))) unsigned int lds_u32_t;
typedef __attribute__((address_space(1))) unsigned int g_u32_t;
#define GLL16(gp, lp)                                                        \
  __builtin_amdgcn_global_load_lds((const g_u32_t*)(gp), (lds_u32_t*)(lp),   \
                                   16, 0, 0)
#endif
#endif

__device__ __forceinline__ unsigned short f2bf(float f) {
  unsigned int u = __builtin_bit_cast(unsigned int, f);
  u += 0x7FFFu + ((u >> 16) & 1u);
  return (unsigned short)(u >> 16);
}
__device__ __forceinline__ unsigned int pack_bf(float a, float b) {
  unsigned int ua = __builtin_bit_cast(unsigned int, a) + 0x8000u;
  unsigned int ub = __builtin_bit_cast(unsigned int, b) + 0x8000u;
  return __builtin_amdgcn_perm(ub, ua, 0x07060302u);
}
__device__ __forceinline__ float bf2f(unsigned short s) {
  unsigned int u = ((unsigned int)s) << 16;
  return __builtin_bit_cast(float, u);
}

// ---------------- fp32 -> bf16 (same layout) ----------------
__global__ __launch_bounds__(256) void f32_to_bf16_kernel(
    const float* __restrict__ in, unsigned short* __restrict__ out, int n4) {
  int i = blockIdx.x * 256 + threadIdx.x;
  if (i < n4) {
    float4 v = ((const float4*)in)[i];
    ushort4 o;
    o.x = f2bf(v.x); o.y = f2bf(v.y); o.z = f2bf(v.z); o.w = f2bf(v.w);
    ((ushort4*)out)[i] = o;
  }
}

// ---------------- W [K,N] fp32 -> Wt [N,K] bf16 ----------------
__global__ __launch_bounds__(256) void transpose_bf16_kernel(
    const float* __restrict__ W, unsigned short* __restrict__ Wt, int K, int N) {
  __shared__ float tile[32][33];
  const int n0 = blockIdx.x * 32, k0 = blockIdx.y * 32;
  const int r = threadIdx.x >> 3, c4 = threadIdx.x & 7;
  float4 v = *(const float4*)(W + (size_t)(k0 + r) * N + n0 + c4 * 4);
  tile[r][c4 * 4 + 0] = v.x;
  tile[r][c4 * 4 + 1] = v.y;
  tile[r][c4 * 4 + 2] = v.z;
  tile[r][c4 * 4 + 3] = v.w;
  __syncthreads();
  ushort4 o;
  o.x = f2bf(tile[c4 * 4 + 0][r]);
  o.y = f2bf(tile[c4 * 4 + 1][r]);
  o.z = f2bf(tile[c4 * 4 + 2][r]);
  o.w = f2bf(tile[c4 * 4 + 3][r]);
  *(ushort4*)(Wt + (size_t)(n0 + r) * K + k0 + c4 * 4) = o;
}

// ---------------- bf16 MFMA GEMM: C[M,N] = A[M,K] @ Bt[N,K]^T ----------------
template <int MODE>
__global__ __launch_bounds__(256) void gemm_bt(
    const unsigned short* __restrict__ A, const unsigned short* __restrict__ Bt,
    float* __restrict__ Cout, unsigned short* __restrict__ qp,
    unsigned short* __restrict__ kp, unsigned short* __restrict__ vp,
    int M, int N, int K) {
  __shared__ __align__(16) unsigned short As[128 * 32];
  __shared__ __align__(16) unsigned short Bs[128 * 32];
  const int tid = threadIdx.x;
  const int lane = tid & 63, w = tid >> 6;
  const int wr = w & 1, wc = w >> 1;
  const int l15 = lane & 15, quad = lane >> 4;
  const int m0 = blockIdx.y * 128, n0 = blockIdx.x * 128;

  const int srow = lane >> 2;
  const int schunk = (lane & 3) * 8;
  const unsigned short* gA = A + (size_t)(m0 + w * 32 + srow) * K + schunk;
  const unsigned short* gB = Bt + (size_t)(n0 + w * 32 + srow) * K + schunk;
  unsigned short* lA0 = &As[(w * 32) * 32 + lane * 8];
  unsigned short* lA1 = &As[(w * 32 + 16) * 32 + lane * 8];
  unsigned short* lB0 = &Bs[(w * 32) * 32 + lane * 8];
  unsigned short* lB1 = &Bs[(w * 32 + 16) * 32 + lane * 8];

  f32x4 acc[4][4] = {};

  for (int k0 = 0; k0 < K; k0 += 32) {
    __syncthreads();
#ifdef HAVE_GLL
    GLL16(gA + k0, lA0);
    GLL16(gA + (size_t)16 * K + k0, lA1);
    GLL16(gB + k0, lB0);
    GLL16(gB + (size_t)16 * K + k0, lB1);
#else
    *(uint4*)lA0 = *(const uint4*)(gA + k0);
    *(uint4*)lA1 = *(const uint4*)(gA + (size_t)16 * K + k0);
    *(uint4*)lB0 = *(const uint4*)(gB + k0);
    *(uint4*)lB1 = *(const uint4*)(gB + (size_t)16 * K + k0);
#endif
    __syncthreads();

    bf16x8 af[4], bfr[4];
#pragma unroll
    for (int mf = 0; mf < 4; ++mf)
      af[mf] = *(const bf16x8*)&As[(wr * 64 + mf * 16 + l15) * 32 + quad * 8];
#pragma unroll
    for (int nf = 0; nf < 4; ++nf)
      bfr[nf] = *(const bf16x8*)&Bs[(wc * 64 + nf * 16 + l15) * 32 + quad * 8];
#pragma unroll
    for (int mf = 0; mf < 4; ++mf)
#pragma unroll
      for (int nf = 0; nf < 4; ++nf)
        acc[mf][nf] = __builtin_amdgcn_mfma_f32_16x16x32_bf16(
            af[mf], bfr[nf], acc[mf][nf], 0, 0, 0);
  }

#pragma unroll
  for (int mf = 0; mf < 4; ++mf) {
    const int row0 = m0 + wr * 64 + mf * 16 + quad * 4;
#pragma unroll
    for (int nf = 0; nf < 4; ++nf) {
      if (MODE == 0) {
#pragma unroll
        for (int r = 0; r < 4; ++r) {
          const int col = n0 + wc * 64 + nf * 16 + l15;
          Cout[(size_t)(row0 + r) * N + col] = acc[mf][nf][r];
        }
      } else {
        const int col = n0 + wc * 64 + nf * 16 + l15;
        const int which = col >> 10;
        const int rem = col & (C - 1);
        const int h = rem >> 6, hd = rem & 63;
        const int b = row0 >> 11, t0 = row0 & (T - 1);
        if (which == 2) {
          ushort4 pv;
          pv.x = f2bf(acc[mf][nf][0]);
          pv.y = f2bf(acc[mf][nf][1]);
          pv.z = f2bf(acc[mf][nf][2]);
          pv.w = f2bf(acc[mf][nf][3]);
          *(ushort4*)(vp + (((size_t)(b * H + h)) * HD + hd) * T + t0) = pv;
        } else {
          unsigned short* dst = which == 0 ? qp : kp;
#pragma unroll
          for (int r = 0; r < 4; ++r)
            dst[(((size_t)(b * H + h)) * T + t0 + r) * HD + hd] =
                f2bf(acc[mf][nf][r]);
        }
      }
    }
  }
}

// ---------------- RoPE in place on bf16 q,k [B,H,T,HD] ----------------
__global__ __launch_bounds__(256) void rope_bf16(unsigned short* __restrict__ q,
                                                 unsigned short* __restrict__ k,
                                                 const int* __restrict__ idx) {
  const size_t g = (size_t)blockIdx.x * 8 + (threadIdx.x >> 5);
  const int lane = threadIdx.x & 31;
  const int t = (int)(g & (size_t)(T - 1));
  const int bh = (int)(g >> 11);
  const int b = bh >> 4;
  const int pos = idx[b * T + t];
  const float inv = 1.0f / powf(10000.0f, (float)lane * (1.0f / 32.0f));
  float sn, cs;
  sincosf((float)pos * inv, &sn, &cs);
  const size_t base = g * (size_t)HD;
  float x1 = bf2f(q[base + lane]), x2 = bf2f(q[base + 32 + lane]);
  q[base + lane]      = f2bf(x1 * cs - x2 * sn);
  q[base + 32 + lane] = f2bf(x1 * sn + x2 * cs);
  x1 = bf2f(k[base + lane]);
  x2 = bf2f(k[base + 32 + lane]);
  k[base + lane]      = f2bf(x1 * cs - x2 * sn);
  k[base + 32 + lane] = f2bf(x1 * sn + x2 * cs);
}

// ---------------- MFMA flash attention, balanced + prefetched ----------------
// Block bx handles mirror q-tile pair (bx, 31-bx); every wave runs exactly
// 33 k-iterations -> uniform duration, full co-residency (4 blocks/CU).
// Wave w owns 16 q-rows of each tile. Barrier-free; K prefetched into dead
// registers after S-MFMA; V issued before softmax. lane=qrow throughout.
__global__ __launch_bounds__(256, 4) void flash_attn_mfma(
    const unsigned short* __restrict__ q, const unsigned short* __restrict__ k,
    const unsigned short* __restrict__ vt, const int* __restrict__ idx,
    unsigned short* __restrict__ y) {
  __shared__ __align__(16) unsigned short Pq[64][72];  // wave-private 16-row slabs

  const int tid = threadIdx.x;
  const int lane = tid & 63, w = tid >> 6;
  const int l15 = lane & 15, quad = lane >> 4;
  const int bx = blockIdx.x, h = blockIdx.y, b = blockIdx.z;
  const size_t bh = (size_t)(b * H + h);
  const unsigned short* qg = q + bh * T * HD;
  const unsigned short* kg = k + bh * T * HD;
  const unsigned short* vg = vt + bh * HD * T;
  const int* idxb = idx + b * T;
  const float SC = 0.18033688f;  // 0.125 * log2(e)

  for (int ti = 0; ti < 2; ++ti) {
    const int qt = (ti == 0) ? bx : 31 - bx;
    const int q0 = qt * 64;
    const int qrow = q0 + w * 16 + l15;  // this lane's q row

    const bf16x8 bq0 = *(const bf16x8*)(qg + (size_t)qrow * HD + quad * 8);
    const bf16x8 bq1 = *(const bf16x8*)(qg + (size_t)qrow * HD + 32 + quad * 8);
    const int pq = idxb[qrow];

    float m_run = -1e38f, l_run = 0.0f;
    f32x4 Oa[4] = {};

    // preload K fragments for kt=0
    bf16x8 ak[4][2];
#pragma unroll
    for (int nf = 0; nf < 4; ++nf) {
      const unsigned short* kr = kg + (size_t)(nf * 16 + l15) * HD;
      ak[nf][0] = *(const bf16x8*)(kr + quad * 8);
      ak[nf][1] = *(const bf16x8*)(kr + 32 + quad * 8);
    }

    for (int kt = 0; kt <= qt; ++kt) {
      const int k0 = kt * 64;

      // S^T: lane = qrow, reg r of tile nf = key nf*16+quad*4+r
      f32x4 Sa[4];
#pragma unroll
      for (int nf = 0; nf < 4; ++nf) {
        f32x4 s = {};
        s = __builtin_amdgcn_mfma_f32_16x16x32_bf16(ak[nf][0], bq0, s, 0, 0, 0);
        s = __builtin_amdgcn_mfma_f32_16x16x32_bf16(ak[nf][1], bq1, s, 0, 0, 0);
        Sa[nf] = s;
      }

      // issue V loads for this tile (consumed after softmax)
      bf16x8 av[4][2];
#pragma unroll
      for (int nfd = 0; nfd < 4; ++nfd) {
        const unsigned short* vr = vg + (size_t)(nfd * 16 + l15) * T + k0;
        av[nfd][0] = *(const bf16x8*)(vr + quad * 8);
        av[nfd][1] = *(const bf16x8*)(vr + 32 + quad * 8);
      }
      // prefetch K for kt+1 into the now-dead ak registers
      {
        const int k0n = (kt < qt) ? k0 + 64 : k0;
#pragma unroll
        for (int nf = 0; nf < 4; ++nf) {
          const unsigned short* kr = kg + (size_t)(k0n + nf * 16 + l15) * HD;
          ak[nf][0] = *(const bf16x8*)(kr + quad * 8);
          ak[nf][1] = *(const bf16x8*)(kr + 32 + quad * 8);
        }
      }

      // scale + mask
      float z[4][4];
#pragma unroll
      for (int nf = 0; nf < 4; ++nf) {
        const int4 pk4 = *(const int4*)(idxb + k0 + nf * 16 + quad * 4);
        z[nf][0] = (pk4.x > pq) ? -3e38f : Sa[nf][0] * SC;
        z[nf][1] = (pk4.y > pq) ? -3e38f : Sa[nf][1] * SC;
        z[nf][2] = (pk4.z > pq) ? -3e38f : Sa[nf][2] * SC;
        z[nf][3] = (pk4.w > pq) ? -3e38f : Sa[nf][3] * SC;
      }

      // online softmax (exp2 domain), row lives in lane -> 2 shfls per reduce
      float mx = z[0][0];
#pragma unroll
      for (int nf = 0; nf < 4; ++nf)
#pragma unroll
        for (int r = 0; r < 4; ++r) mx = fmaxf(mx, z[nf][r]);
      mx = fmaxf(mx, __shfl_xor(mx, 16));
      mx = fmaxf(mx, __shfl_xor(mx, 32));
      const float mn = fmaxf(m_run, mx);
      const float alpha = exp2f(m_run - mn);
      m_run = mn;
      float sum = 0.0f;
#pragma unroll
      for (int nf = 0; nf < 4; ++nf)
#pragma unroll
        for (int r = 0; r < 4; ++r) {
          float p = exp2f(z[nf][r] - mn);
          z[nf][r] = p;
          sum += p;
        }
      sum += __shfl_xor(sum, 16);
      sum += __shfl_xor(sum, 32);
      l_run = l_run * alpha + sum;

      // P -> LDS (wave-private rows)
#pragma unroll
      for (int nf = 0; nf < 4; ++nf) {
        uint2 pw;
        pw.x = pack_bf(z[nf][0], z[nf][1]);
        pw.y = pack_bf(z[nf][2], z[nf][3]);
        *(uint2*)&Pq[w * 16 + l15][nf * 16 + quad * 4] = pw;
      }

      // rescale O (per-lane: lane = qrow)
#pragma unroll
      for (int nfd = 0; nfd < 4; ++nfd)
#pragma unroll
        for (int r = 0; r < 4; ++r) Oa[nfd][r] *= alpha;

      asm volatile("s_waitcnt lgkmcnt(0)" ::: "memory");

      const bf16x8 bp0 = *(const bf16x8*)&Pq[w * 16 + l15][quad * 8];
      const bf16x8 bp1 = *(const bf16x8*)&Pq[w * 16 + l15][32 + quad * 8];

      // O^T += V^T · P^T
#pragma unroll
      for (int nfd = 0; nfd < 4; ++nfd) {
        Oa[nfd] = __builtin_amdgcn_mfma_f32_16x16x32_bf16(av[nfd][0], bp0, Oa[nfd], 0, 0, 0);
        Oa[nfd] = __builtin_amdgcn_mfma_f32_16x16x32_bf16(av[nfd][1], bp1, Oa[nfd], 0, 0, 0);
      }
    }

    // epilogue: lane = qrow, (quad,reg) = d -> b64 stores
    const float rl = 1.0f / l_run;
    const size_t base = ((size_t)b * T + qrow) * (size_t)C + h * HD;
#pragma unroll
    for (int nfd = 0; nfd < 4; ++nfd) {
      ushort4 o;
      o.x = f2bf(Oa[nfd][0] * rl);
      o.y = f2bf(Oa[nfd][1] * rl);
      o.z = f2bf(Oa[nfd][2] * rl);
      o.w = f2bf(Oa[nfd][3] * rl);
      *(ushort4*)(y + base + nfd * 16 + quad * 4) = o;
    }
  }
}

}  // namespace

extern "C" void kernel_launch(void* const* d_in, const int* in_sizes, int n_in,
                              void* d_out, int out_size, void* d_ws,
                              size_t ws_size, hipStream_t stream) {
  const float* x      = (const float*)d_in[0];
  const float* W_attn = (const float*)d_in[1];
  const float* W_proj = (const float*)d_in[2];
  const int* indices  = (const int*)d_in[3];
  float* out = (float*)d_out;

  const size_t nM = (size_t)Bsz * T * C;
  unsigned short* xb  = (unsigned short*)d_ws;
  unsigned short* wat = xb + nM;
  unsigned short* wpt = wat + (size_t)3 * C * C;
  unsigned short* qp  = wpt + (size_t)C * C;           // [B,H,T,HD]
  unsigned short* kp  = qp + nM;                       // [B,H,T,HD]
  unsigned short* vp  = kp + nM;                       // [B,H,HD,T]
  unsigned short* yb  = vp + nM;                       // [B,T,C]

  f32_to_bf16_kernel<<<(int)(nM / 4 / 256), 256, 0, stream>>>(x, xb, (int)(nM / 4));
  transpose_bf16_kernel<<<dim3(3 * C / 32, C / 32), 256, 0, stream>>>(W_attn, wat, C, 3 * C);
  transpose_bf16_kernel<<<dim3(C / 32, C / 32), 256, 0, stream>>>(W_proj, wpt, C, C);
  gemm_bt<1><<<dim3(3 * C / 128, Bsz * T / 128), 256, 0, stream>>>(
      xb, wat, nullptr, qp, kp, vp, Bsz * T, 3 * C, C);
  rope_bf16<<<(Bsz * H * T) / 8, 256, 0, stream>>>(qp, kp, indices);
  flash_attn_mfma<<<dim3(16, H, Bsz), 256, 0, stream>>>(qp, kp, vp, indices, yb);
  gemm_bt<0><<<dim3(C / 128, Bsz * T / 128), 256, 0, stream>>>(
      yb, wpt, out, nullptr, nullptr, nullptr, Bsz * T, C, C);
}

// Round 6
// 347.887 us; speedup vs baseline: 1.5451x; 1.5451x over previous
//
#include <hip/hip_runtime.h>
#include <math.h>

namespace {
constexpr int Bsz = 4;
constexpr int T   = 2048;
constexpr int C   = 1024;
constexpr int H   = 16;
constexpr int HD  = 64;

typedef short bf16x8 __attribute__((ext_vector_type(8)));
typedef float f32x4  __attribute__((ext_vector_type(4)));

#if defined(__has_builtin)
#if __has_builtin(__builtin_amdgcn_global_load_lds)
#define HAVE_GLL 1
typedef __attribute__((address_space(3))) unsigned int lds_u32_t;
typedef __attribute__((address_space(1))) unsigned int g_u32_t;
#define GLL16(gp, lp)                                                        \
  __builtin_amdgcn_global_load_lds((const g_u32_t*)(gp), (lds_u32_t*)(lp),   \
                                   16, 0, 0)
#endif
#endif

__device__ __forceinline__ unsigned short f2bf(float f) {
  unsigned int u = __builtin_bit_cast(unsigned int, f);
  u += 0x7FFFu + ((u >> 16) & 1u);
  return (unsigned short)(u >> 16);
}
__device__ __forceinline__ unsigned int pack_bf(float a, float b) {
  unsigned int ua = __builtin_bit_cast(unsigned int, a) + 0x8000u;
  unsigned int ub = __builtin_bit_cast(unsigned int, b) + 0x8000u;
  return __builtin_amdgcn_perm(ub, ua, 0x07060302u);
}
__device__ __forceinline__ float bf2f(unsigned short s) {
  unsigned int u = ((unsigned int)s) << 16;
  return __builtin_bit_cast(float, u);
}

// ---------------- fp32 -> bf16 (same layout) ----------------
__global__ __launch_bounds__(256) void f32_to_bf16_kernel(
    const float* __restrict__ in, unsigned short* __restrict__ out, int n4) {
  int i = blockIdx.x * 256 + threadIdx.x;
  if (i < n4) {
    float4 v = ((const float4*)in)[i];
    ushort4 o;
    o.x = f2bf(v.x); o.y = f2bf(v.y); o.z = f2bf(v.z); o.w = f2bf(v.w);
    ((ushort4*)out)[i] = o;
  }
}

// ---------------- W [K,N] fp32 -> Wt [N,K] bf16 ----------------
__global__ __launch_bounds__(256) void transpose_bf16_kernel(
    const float* __restrict__ W, unsigned short* __restrict__ Wt, int K, int N) {
  __shared__ float tile[32][33];
  const int n0 = blockIdx.x * 32, k0 = blockIdx.y * 32;
  const int r = threadIdx.x >> 3, c4 = threadIdx.x & 7;
  float4 v = *(const float4*)(W + (size_t)(k0 + r) * N + n0 + c4 * 4);
  tile[r][c4 * 4 + 0] = v.x;
  tile[r][c4 * 4 + 1] = v.y;
  tile[r][c4 * 4 + 2] = v.z;
  tile[r][c4 * 4 + 3] = v.w;
  __syncthreads();
  ushort4 o;
  o.x = f2bf(tile[c4 * 4 + 0][r]);
  o.y = f2bf(tile[c4 * 4 + 1][r]);
  o.z = f2bf(tile[c4 * 4 + 2][r]);
  o.w = f2bf(tile[c4 * 4 + 3][r]);
  *(ushort4*)(Wt + (size_t)(n0 + r) * K + k0 + c4 * 4) = o;
}

// ---------------- bf16 MFMA GEMM: C[M,N] = A[M,K] @ Bt[N,K]^T ----------------
template <int MODE>
__global__ __launch_bounds__(256) void gemm_bt(
    const unsigned short* __restrict__ A, const unsigned short* __restrict__ Bt,
    float* __restrict__ Cout, unsigned short* __restrict__ qp,
    unsigned short* __restrict__ kp, unsigned short* __restrict__ vp,
    int M, int N, int K) {
  __shared__ __align__(16) unsigned short As[128 * 32];
  __shared__ __align__(16) unsigned short Bs[128 * 32];
  const int tid = threadIdx.x;
  const int lane = tid & 63, w = tid >> 6;
  const int wr = w & 1, wc = w >> 1;
  const int l15 = lane & 15, quad = lane >> 4;
  const int m0 = blockIdx.y * 128, n0 = blockIdx.x * 128;

  const int srow = lane >> 2;
  const int schunk = (lane & 3) * 8;
  const unsigned short* gA = A + (size_t)(m0 + w * 32 + srow) * K + schunk;
  const unsigned short* gB = Bt + (size_t)(n0 + w * 32 + srow) * K + schunk;
  unsigned short* lA0 = &As[(w * 32) * 32 + lane * 8];
  unsigned short* lA1 = &As[(w * 32 + 16) * 32 + lane * 8];
  unsigned short* lB0 = &Bs[(w * 32) * 32 + lane * 8];
  unsigned short* lB1 = &Bs[(w * 32 + 16) * 32 + lane * 8];

  f32x4 acc[4][4] = {};

  for (int k0 = 0; k0 < K; k0 += 32) {
    __syncthreads();
#ifdef HAVE_GLL
    GLL16(gA + k0, lA0);
    GLL16(gA + (size_t)16 * K + k0, lA1);
    GLL16(gB + k0, lB0);
    GLL16(gB + (size_t)16 * K + k0, lB1);
#else
    *(uint4*)lA0 = *(const uint4*)(gA + k0);
    *(uint4*)lA1 = *(const uint4*)(gA + (size_t)16 * K + k0);
    *(uint4*)lB0 = *(const uint4*)(gB + k0);
    *(uint4*)lB1 = *(const uint4*)(gB + (size_t)16 * K + k0);
#endif
    __syncthreads();

    bf16x8 af[4], bfr[4];
#pragma unroll
    for (int mf = 0; mf < 4; ++mf)
      af[mf] = *(const bf16x8*)&As[(wr * 64 + mf * 16 + l15) * 32 + quad * 8];
#pragma unroll
    for (int nf = 0; nf < 4; ++nf)
      bfr[nf] = *(const bf16x8*)&Bs[(wc * 64 + nf * 16 + l15) * 32 + quad * 8];
#pragma unroll
    for (int mf = 0; mf < 4; ++mf)
#pragma unroll
      for (int nf = 0; nf < 4; ++nf)
        acc[mf][nf] = __builtin_amdgcn_mfma_f32_16x16x32_bf16(
            af[mf], bfr[nf], acc[mf][nf], 0, 0, 0);
  }

#pragma unroll
  for (int mf = 0; mf < 4; ++mf) {
    const int row0 = m0 + wr * 64 + mf * 16 + quad * 4;
#pragma unroll
    for (int nf = 0; nf < 4; ++nf) {
      if (MODE == 0) {
#pragma unroll
        for (int r = 0; r < 4; ++r) {
          const int col = n0 + wc * 64 + nf * 16 + l15;
          Cout[(size_t)(row0 + r) * N + col] = acc[mf][nf][r];
        }
      } else {
        const int col = n0 + wc * 64 + nf * 16 + l15;
        const int which = col >> 10;
        const int rem = col & (C - 1);
        const int h = rem >> 6, hd = rem & 63;
        const int b = row0 >> 11, t0 = row0 & (T - 1);
        if (which == 2) {
          ushort4 pv;
          pv.x = f2bf(acc[mf][nf][0]);
          pv.y = f2bf(acc[mf][nf][1]);
          pv.z = f2bf(acc[mf][nf][2]);
          pv.w = f2bf(acc[mf][nf][3]);
          *(ushort4*)(vp + (((size_t)(b * H + h)) * HD + hd) * T + t0) = pv;
        } else {
          unsigned short* dst = which == 0 ? qp : kp;
#pragma unroll
          for (int r = 0; r < 4; ++r)
            dst[(((size_t)(b * H + h)) * T + t0 + r) * HD + hd] =
                f2bf(acc[mf][nf][r]);
        }
      }
    }
  }
}

// ---------------- RoPE in place on bf16 q,k [B,H,T,HD] ----------------
__global__ __launch_bounds__(256) void rope_bf16(unsigned short* __restrict__ q,
                                                 unsigned short* __restrict__ k,
                                                 const int* __restrict__ idx) {
  const size_t g = (size_t)blockIdx.x * 8 + (threadIdx.x >> 5);
  const int lane = threadIdx.x & 31;
  const int t = (int)(g & (size_t)(T - 1));
  const int bh = (int)(g >> 11);
  const int b = bh >> 4;
  const int pos = idx[b * T + t];
  const float inv = 1.0f / powf(10000.0f, (float)lane * (1.0f / 32.0f));
  float sn, cs;
  sincosf((float)pos * inv, &sn, &cs);
  const size_t base = g * (size_t)HD;
  float x1 = bf2f(q[base + lane]), x2 = bf2f(q[base + 32 + lane]);
  q[base + lane]      = f2bf(x1 * cs - x2 * sn);
  q[base + 32 + lane] = f2bf(x1 * sn + x2 * cs);
  x1 = bf2f(k[base + lane]);
  x2 = bf2f(k[base + 32 + lane]);
  k[base + lane]      = f2bf(x1 * cs - x2 * sn);
  k[base + 32 + lane] = f2bf(x1 * sn + x2 * cs);
}

// ---------------- MFMA flash attention ----------------
// Mirror-pair balance: block bx handles q-tiles {bx, 31-bx} (64 rows each)
// -> every block runs exactly 33 k-iterations. 4 waves each own 16 q-rows.
// K/V double-buffered in LDS: global loads for kt+1 issue at iter top
// (latency hidden under compute of kt), ds_write to the spare buffer at
// iter end; ONE barrier per iteration. S^T/O^T formulation keeps the
// softmax row in the lane dimension (2 shfls per reduction, per-lane
// alpha/l). No launch_bounds min -> no spill (R5 lesson).
__global__ __launch_bounds__(256) void flash_attn_mfma(
    const unsigned short* __restrict__ q, const unsigned short* __restrict__ k,
    const unsigned short* __restrict__ vt, const int* __restrict__ idx,
    unsigned short* __restrict__ y) {
  __shared__ __align__(16) unsigned short Ks[2][64][72];   // [buf][key][d]
  __shared__ __align__(16) unsigned short Vts[2][64][72];  // [buf][d][key]
  __shared__ __align__(16) unsigned short Pq[64][72];      // [qrow][key]

  const int tid = threadIdx.x;
  const int lane = tid & 63, w = tid >> 6;
  const int l15 = lane & 15, quad = lane >> 4;
  const int bx = blockIdx.x, h = blockIdx.y, b = blockIdx.z;
  const size_t bh = (size_t)(b * H + h);
  const unsigned short* qg = q + bh * T * HD;
  const unsigned short* kg = k + bh * T * HD;
  const unsigned short* vg = vt + bh * HD * T;
  const int* idxb = idx + b * T;
  const float SC = 0.18033688f;  // 0.125 * log2(e)

  // staging coords: 64 rows x 8 chunks(16B) = 512 -> 2 per thread
  const int r1 = tid >> 3, c1 = tid & 7;
  const int r2 = r1 + 32;

  for (int ti = 0; ti < 2; ++ti) {
    const int qt = (ti == 0) ? bx : 31 - bx;
    const int q0 = qt * 64;
    const int qrow = q0 + w * 16 + l15;  // this lane's q row

    const bf16x8 bq0 = *(const bf16x8*)(qg + (size_t)qrow * HD + quad * 8);
    const bf16x8 bq1 = *(const bf16x8*)(qg + (size_t)qrow * HD + 32 + quad * 8);
    const int pq = idxb[qrow];

    float m_run = -1e38f, l_run = 0.0f;
    f32x4 Oa[4] = {};

    // prologue: stage kt=0 into buf 0
    {
      uint4 ka = *(const uint4*)(kg + (size_t)r1 * HD + c1 * 8);
      uint4 kb = *(const uint4*)(kg + (size_t)r2 * HD + c1 * 8);
      uint4 va = *(const uint4*)(vg + (size_t)r1 * T + c1 * 8);
      uint4 vb = *(const uint4*)(vg + (size_t)r2 * T + c1 * 8);
      __syncthreads();  // all waves done with previous tile's buffers
      *(uint4*)&Ks[0][r1][c1 * 8] = ka;
      *(uint4*)&Ks[0][r2][c1 * 8] = kb;
      *(uint4*)&Vts[0][r1][c1 * 8] = va;
      *(uint4*)&Vts[0][r2][c1 * 8] = vb;
    }

    for (int kt = 0; kt <= qt; ++kt) {
      const int cur = kt & 1;
      const int k0 = kt * 64;
      __syncthreads();  // stage(kt) visible; buf[cur^1] free for restaging

      // issue global loads for kt+1 now; consumed at iteration end
      uint4 nka, nkb, nva, nvb;
      if (kt < qt) {
        const int kn = k0 + 64;
        nka = *(const uint4*)(kg + (size_t)(kn + r1) * HD + c1 * 8);
        nkb = *(const uint4*)(kg + (size_t)(kn + r2) * HD + c1 * 8);
        nva = *(const uint4*)(vg + (size_t)r1 * T + kn + c1 * 8);
        nvb = *(const uint4*)(vg + (size_t)r2 * T + kn + c1 * 8);
      }

      // S^T = K·Q^T : lane = qrow, reg r of tile nf = key nf*16+quad*4+r
      f32x4 Sa[4];
#pragma unroll
      for (int nf = 0; nf < 4; ++nf) {
        bf16x8 ak0 = *(const bf16x8*)&Ks[cur][nf * 16 + l15][quad * 8];
        bf16x8 ak1 = *(const bf16x8*)&Ks[cur][nf * 16 + l15][32 + quad * 8];
        f32x4 s = {};
        s = __builtin_amdgcn_mfma_f32_16x16x32_bf16(ak0, bq0, s, 0, 0, 0);
        s = __builtin_amdgcn_mfma_f32_16x16x32_bf16(ak1, bq1, s, 0, 0, 0);
        Sa[nf] = s;
      }

      // scale + mask
      float z[4][4];
#pragma unroll
      for (int nf = 0; nf < 4; ++nf) {
        const int4 pk4 = *(const int4*)(idxb + k0 + nf * 16 + quad * 4);
        z[nf][0] = (pk4.x > pq) ? -3e38f : Sa[nf][0] * SC;
        z[nf][1] = (pk4.y > pq) ? -3e38f : Sa[nf][1] * SC;
        z[nf][2] = (pk4.z > pq) ? -3e38f : Sa[nf][2] * SC;
        z[nf][3] = (pk4.w > pq) ? -3e38f : Sa[nf][3] * SC;
      }

      // online softmax (exp2 domain); row lives in lane -> 2 shfls per reduce
      float mx = z[0][0];
#pragma unroll
      for (int nf = 0; nf < 4; ++nf)
#pragma unroll
        for (int r = 0; r < 4; ++r) mx = fmaxf(mx, z[nf][r]);
      mx = fmaxf(mx, __shfl_xor(mx, 16));
      mx = fmaxf(mx, __shfl_xor(mx, 32));
      const float mn = fmaxf(m_run, mx);
      const float alpha = exp2f(m_run - mn);
      m_run = mn;
      float sum = 0.0f;
#pragma unroll
      for (int nf = 0; nf < 4; ++nf)
#pragma unroll
        for (int r = 0; r < 4; ++r) {
          float p = exp2f(z[nf][r] - mn);
          z[nf][r] = p;
          sum += p;
        }
      sum += __shfl_xor(sum, 16);
      sum += __shfl_xor(sum, 32);
      l_run = l_run * alpha + sum;

      // P -> LDS (wave-private rows)
#pragma unroll
      for (int nf = 0; nf < 4; ++nf) {
        uint2 pw;
        pw.x = pack_bf(z[nf][0], z[nf][1]);
        pw.y = pack_bf(z[nf][2], z[nf][3]);
        *(uint2*)&Pq[w * 16 + l15][nf * 16 + quad * 4] = pw;
      }

      // rescale O (per-lane: lane = qrow)
#pragma unroll
      for (int nfd = 0; nfd < 4; ++nfd)
#pragma unroll
        for (int r = 0; r < 4; ++r) Oa[nfd][r] *= alpha;

      asm volatile("s_waitcnt lgkmcnt(0)" ::: "memory");

      const bf16x8 bp0 = *(const bf16x8*)&Pq[w * 16 + l15][quad * 8];
      const bf16x8 bp1 = *(const bf16x8*)&Pq[w * 16 + l15][32 + quad * 8];

      // O^T += V^T · P^T
#pragma unroll
      for (int nfd = 0; nfd < 4; ++nfd) {
        bf16x8 av0 = *(const bf16x8*)&Vts[cur][nfd * 16 + l15][quad * 8];
        bf16x8 av1 = *(const bf16x8*)&Vts[cur][nfd * 16 + l15][32 + quad * 8];
        Oa[nfd] = __builtin_amdgcn_mfma_f32_16x16x32_bf16(av0, bp0, Oa[nfd], 0, 0, 0);
        Oa[nfd] = __builtin_amdgcn_mfma_f32_16x16x32_bf16(av1, bp1, Oa[nfd], 0, 0, 0);
      }

      // write next tile into the spare buffer (waits its loads via dep)
      if (kt < qt) {
        const int nxt = cur ^ 1;
        *(uint4*)&Ks[nxt][r1][c1 * 8] = nka;
        *(uint4*)&Ks[nxt][r2][c1 * 8] = nkb;
        *(uint4*)&Vts[nxt][r1][c1 * 8] = nva;
        *(uint4*)&Vts[nxt][r2][c1 * 8] = nvb;
      }
    }

    // epilogue: lane = qrow, (quad,reg) = d -> b64 stores
    const float rl = 1.0f / l_run;
    const size_t base = ((size_t)b * T + qrow) * (size_t)C + h * HD;
#pragma unroll
    for (int nfd = 0; nfd < 4; ++nfd) {
      ushort4 o;
      o.x = f2bf(Oa[nfd][0] * rl);
      o.y = f2bf(Oa[nfd][1] * rl);
      o.z = f2bf(Oa[nfd][2] * rl);
      o.w = f2bf(Oa[nfd][3] * rl);
      *(ushort4*)(y + base + nfd * 16 + quad * 4) = o;
    }
  }
}

}  // namespace

extern "C" void kernel_launch(void* const* d_in, const int* in_sizes, int n_in,
                              void* d_out, int out_size, void* d_ws,
                              size_t ws_size, hipStream_t stream) {
  const float* x      = (const float*)d_in[0];
  const float* W_attn = (const float*)d_in[1];
  const float* W_proj = (const float*)d_in[2];
  const int* indices  = (const int*)d_in[3];
  float* out = (float*)d_out;

  const size_t nM = (size_t)Bsz * T * C;
  unsigned short* xb  = (unsigned short*)d_ws;
  unsigned short* wat = xb + nM;
  unsigned short* wpt = wat + (size_t)3 * C * C;
  unsigned short* qp  = wpt + (size_t)C * C;           // [B,H,T,HD]
  unsigned short* kp  = qp + nM;                       // [B,H,T,HD]
  unsigned short* vp  = kp + nM;                       // [B,H,HD,T]
  unsigned short* yb  = vp + nM;                       // [B,T,C]

  f32_to_bf16_kernel<<<(int)(nM / 4 / 256), 256, 0, stream>>>(x, xb, (int)(nM / 4));
  transpose_bf16_kernel<<<dim3(3 * C / 32, C / 32), 256, 0, stream>>>(W_attn, wat, C, 3 * C);
  transpose_bf16_kernel<<<dim3(C / 32, C / 32), 256, 0, stream>>>(W_proj, wpt, C, C);
  gemm_bt<1><<<dim3(3 * C / 128, Bsz * T / 128), 256, 0, stream>>>(
      xb, wat, nullptr, qp, kp, vp, Bsz * T, 3 * C, C);
  rope_bf16<<<(Bsz * H * T) / 8, 256, 0, stream>>>(qp, kp, indices);
  flash_attn_mfma<<<dim3(16, H, Bsz), 256, 0, stream>>>(qp, kp, vp, indices, yb);
  gemm_bt<0><<<dim3(C / 128, Bsz * T / 128), 256, 0, stream>>>(
      yb, wpt, out, nullptr, nullptr, nullptr, Bsz * T, C, C);
}